// Round 1
// baseline (2310.572 us; speedup 1.0000x reference)
//
#include <hip/hip_runtime.h>

#define D 1024
#define DT 0.1f

typedef __attribute__((ext_vector_type(8))) __bf16 bf16x8;
typedef __attribute__((ext_vector_type(4))) float floatx4;

__device__ __forceinline__ unsigned short f2bf(float f) {
  unsigned int u = __builtin_bit_cast(unsigned int, f);
  u = u + 0x7fffu + ((u >> 16) & 1u);           // RNE
  return (unsigned short)(u >> 16);
}
__device__ __forceinline__ float bf2f(unsigned short b) {
  return __builtin_bit_cast(float, ((unsigned int)b) << 16);
}

__device__ __forceinline__ void gload_lds16(const void* g, void* l) {
  __builtin_amdgcn_global_load_lds(
      (const __attribute__((address_space(1))) void*)g,
      (__attribute__((address_space(3))) void*)l, 16, 0, 0);
}

// Split fp32 -> (hi, lo) bf16 pair; optionally copy the fp32 source (for traj[0]).
__global__ void __launch_bounds__(256) split_kernel(
    const float* __restrict__ src, float* __restrict__ copy_dst,
    unsigned short* __restrict__ hi, unsigned short* __restrict__ lo) {
  const int i = blockIdx.x * blockDim.x + threadIdx.x;   // one float4 / thread
  float4 v = ((const float4*)src)[i];
  if (copy_dst) ((float4*)copy_dst)[i] = v;
  ushort4 h, l;
  h.x = f2bf(v.x); l.x = f2bf(v.x - bf2f(h.x));
  h.y = f2bf(v.y); l.y = f2bf(v.y - bf2f(h.y));
  h.z = f2bf(v.z); l.z = f2bf(v.z - bf2f(h.z));
  h.w = f2bf(v.w); l.w = f2bf(v.w - bf2f(h.w));
  ((ushort4*)hi)[i] = h;
  ((ushort4*)lo)[i] = l;
}

// One Euler step: z = h @ W_k^T + b ; h' = h + DT*tanh(z)
// A (h) given as bf16 hi/lo, B (W slab) as bf16 hi/lo (row-major [n][k] == B^T layout).
// bf16x3: acc += Ah*Bh + Al*Bh + Ah*Bl  (Al*Bl dropped, ~2^-18)
// 256 blocks x 512 threads; 64x64 tile/block; 8 waves in 4x2 grid, each wave 16x32.
__global__ void __launch_bounds__(512) step_kernel(
    const unsigned short* __restrict__ Ah, const unsigned short* __restrict__ Al,
    const unsigned short* __restrict__ Bh, const unsigned short* __restrict__ Bl,
    const float* __restrict__ bias,
    const float* __restrict__ hprev, float* __restrict__ hnext,
    unsigned short* __restrict__ Nh, unsigned short* __restrict__ Nl,
    float* __restrict__ feat) {
  __shared__ unsigned short lds[4 * 64 * 64];   // sAh | sAl | sBh | sBl, 8 KiB each
  char* ldsb = (char*)lds;

  const int tid  = threadIdx.x;
  const int lane = tid & 63;
  const int wave = tid >> 6;       // 0..7
  const int wr   = wave >> 1;      // 0..3  (rows 16*wr)
  const int wc   = wave & 1;       // 0..1  (cols 32*wc)
  const int row0 = (blockIdx.x >> 4) << 6;
  const int col0 = (blockIdx.x & 15) << 6;
  const int quad = lane >> 4;
  const int l15  = lane & 15;

  // ---- staging: wave stages rows [8*wave, 8*wave+8) of each 64x64 bf16 tile ----
  // LDS row = 128 B = 8 groups of 16 B; storage group g holds source group g^(row&7)
  const int srow = lane >> 3;                  // 0..7 within the wave's 8-row span
  const int sgrp = (lane & 7) ^ srow;          // swizzled source group
  const long aoff = (long)(row0 + wave * 8 + srow) * D + sgrp * 8;
  const long boff = (long)(col0 + wave * 8 + srow) * D + sgrp * 8;
  const unsigned short* gAh = Ah + aoff;
  const unsigned short* gAl = Al + aoff;
  const unsigned short* gBh = Bh + boff;
  const unsigned short* gBl = Bl + boff;
  char* sAh = ldsb + 0     + wave * 1024;      // wave-uniform LDS dest base
  char* sAl = ldsb + 8192  + wave * 1024;
  char* sBh = ldsb + 16384 + wave * 1024;
  char* sBl = ldsb + 24576 + wave * 1024;

  // ---- fragment addressing ----
  const int Ra  = (wr << 4) | l15;             // A row in tile
  const int Rb0 = (wc << 5) | l15;             // B row (= output col) tj=0
  const int Rb1 = Rb0 + 16;                    // tj=1  (same &7 phase)
  const int x7  = lane & 7;                    // == Ra&7 == Rb0&7 == Rb1&7

  floatx4 acc0 = {0.f, 0.f, 0.f, 0.f};
  floatx4 acc1 = {0.f, 0.f, 0.f, 0.f};

  for (int c = 0; c < 16; ++c) {               // K chunks of 64
    const int kk = c << 6;
    gload_lds16(gAh + kk, sAh);
    gload_lds16(gAl + kk, sAl);
    gload_lds16(gBh + kk, sBh);
    gload_lds16(gBl + kk, sBl);
    __syncthreads();
#pragma unroll
    for (int kc = 0; kc < 2; ++kc) {
      const int gs = (((kc << 2) | quad) ^ x7) << 4;   // swizzled 16B-group byte off
      bf16x8 ah  = *(const bf16x8*)(ldsb + 0     + Ra  * 128 + gs);
      bf16x8 al  = *(const bf16x8*)(ldsb + 8192  + Ra  * 128 + gs);
      bf16x8 bh0 = *(const bf16x8*)(ldsb + 16384 + Rb0 * 128 + gs);
      bf16x8 bl0 = *(const bf16x8*)(ldsb + 24576 + Rb0 * 128 + gs);
      bf16x8 bh1 = *(const bf16x8*)(ldsb + 16384 + Rb1 * 128 + gs);
      bf16x8 bl1 = *(const bf16x8*)(ldsb + 24576 + Rb1 * 128 + gs);
      acc0 = __builtin_amdgcn_mfma_f32_16x16x32_bf16(ah, bh0, acc0, 0, 0, 0);
      acc1 = __builtin_amdgcn_mfma_f32_16x16x32_bf16(ah, bh1, acc1, 0, 0, 0);
      acc0 = __builtin_amdgcn_mfma_f32_16x16x32_bf16(al, bh0, acc0, 0, 0, 0);
      acc1 = __builtin_amdgcn_mfma_f32_16x16x32_bf16(al, bh1, acc1, 0, 0, 0);
      acc0 = __builtin_amdgcn_mfma_f32_16x16x32_bf16(ah, bl0, acc0, 0, 0, 0);
      acc1 = __builtin_amdgcn_mfma_f32_16x16x32_bf16(ah, bl1, acc1, 0, 0, 0);
    }
    __syncthreads();
  }

  // ---- epilogue: bias + tanh + Euler update; emit fp32 traj and bf16 hi/lo state ----
  const int ecol = col0 + (wc << 5) + l15;
  const int erow = row0 + (wr << 4) + (quad << 2);
  const float b0 = bias[ecol];
  const float b1 = bias[ecol + 16];
  const bool wf = (feat != nullptr);
#pragma unroll
  for (int r = 0; r < 4; ++r) {
    const long i0 = (long)(erow + r) * D + ecol;
    {
      float f  = tanhf(acc0[r] + b0);
      float hn = hprev[i0] + DT * f;
      hnext[i0] = hn;
      unsigned short hb = f2bf(hn);
      Nh[i0] = hb;
      Nl[i0] = f2bf(hn - bf2f(hb));
      if (wf) feat[i0] = hn;
    }
    {
      const long i1 = i0 + 16;
      float f  = tanhf(acc1[r] + b1);
      float hn = hprev[i1] + DT * f;
      hnext[i1] = hn;
      unsigned short hb = f2bf(hn);
      Nh[i1] = hb;
      Nl[i1] = f2bf(hn - bf2f(hb));
      if (wf) feat[i1] = hn;
    }
  }
}

extern "C" void kernel_launch(void* const* d_in, const int* in_sizes, int n_in,
                              void* d_out, int out_size, void* d_ws, size_t ws_size,
                              hipStream_t stream) {
  const float* x = (const float*)d_in[0];
  const float* W = (const float*)d_in[1];
  const float* b = (const float*)d_in[2];
  float* out  = (float*)d_out;
  float* feat = out;                       // [1024,1024] final features
  float* traj = out + (size_t)D * D;       // [101,1024,1024]

  const size_t M = (size_t)D * D;          // 1M elements
  unsigned short* ws = (unsigned short*)d_ws;   // 12 MB used
  unsigned short* wh    = ws;
  unsigned short* wl    = wh + M;
  unsigned short* h_hi0 = wl + M;
  unsigned short* h_lo0 = h_hi0 + M;
  unsigned short* h_hi1 = h_lo0 + M;
  unsigned short* h_lo1 = h_hi1 + M;
  unsigned short* hh[2] = {h_hi0, h_hi1};
  unsigned short* hl[2] = {h_lo0, h_lo1};

  const int splitBlocks = (int)(M / 4 / 256);   // 1024

  // traj[0] = x; h state (bf16 hi/lo) <- x
  split_kernel<<<splitBlocks, 256, 0, stream>>>(x, traj, hh[0], hl[0]);

  for (int k = 0; k < 10; ++k) {
    // convert W slab k to bf16 hi/lo (reused for 10 steps)
    split_kernel<<<splitBlocks, 256, 0, stream>>>(W + k * M, (float*)nullptr, wh, wl);
    for (int s = 0; s < 10; ++s) {
      const int n = k * 10 + s;
      step_kernel<<<256, 512, 0, stream>>>(
          hh[n & 1], hl[n & 1], wh, wl, b + (size_t)k * D,
          traj + (size_t)n * M, traj + (size_t)(n + 1) * M,
          hh[(n + 1) & 1], hl[(n + 1) & 1],
          (n == 99) ? feat : nullptr);
    }
  }
}

// Round 2
// 1566.094 us; speedup vs baseline: 1.4754x; 1.4754x over previous
//
#include <hip/hip_runtime.h>

#define D 1024
#define DT 0.1f

typedef __attribute__((ext_vector_type(8))) __bf16 bf16x8;
typedef __attribute__((ext_vector_type(4))) float floatx4;

__device__ __forceinline__ unsigned short f2bf(float f) {
  unsigned int u = __builtin_bit_cast(unsigned int, f);
  u = u + 0x7fffu + ((u >> 16) & 1u);           // RNE
  return (unsigned short)(u >> 16);
}
__device__ __forceinline__ float bf2f(unsigned short b) {
  return __builtin_bit_cast(float, ((unsigned int)b) << 16);
}

__device__ __forceinline__ void gload_lds16(const void* g, void* l) {
  __builtin_amdgcn_global_load_lds(
      (const __attribute__((address_space(1))) void*)g,
      (__attribute__((address_space(3))) void*)l, 16, 0, 0);
}

// tanh(x) = sign(x) * (1-e)/(1+e), e = exp(-2|x|)  — e in (0,1], no overflow.
__device__ __forceinline__ float fast_tanh(float x) {
  float ax = __builtin_fabsf(x);
  float e  = __expf(-2.0f * ax);
  float y  = (1.0f - e) * __builtin_amdgcn_rcpf(1.0f + e);
  return __builtin_copysignf(y, x);
}

// Split fp32 -> (hi, lo) bf16 pair; optionally copy the fp32 source (for traj[0]).
__global__ void __launch_bounds__(256) split_kernel(
    const float* __restrict__ src, float* __restrict__ copy_dst,
    unsigned short* __restrict__ hi, unsigned short* __restrict__ lo) {
  const int i = blockIdx.x * blockDim.x + threadIdx.x;   // one float4 / thread
  float4 v = ((const float4*)src)[i];
  if (copy_dst) ((float4*)copy_dst)[i] = v;
  ushort4 h, l;
  h.x = f2bf(v.x); l.x = f2bf(v.x - bf2f(h.x));
  h.y = f2bf(v.y); l.y = f2bf(v.y - bf2f(h.y));
  h.z = f2bf(v.z); l.z = f2bf(v.z - bf2f(h.z));
  h.w = f2bf(v.w); l.w = f2bf(v.w - bf2f(h.w));
  ((ushort4*)hi)[i] = h;
  ((ushort4*)lo)[i] = l;
}

// One Euler step: z = h @ W_k^T + b ; h' = h + DT*tanh(z)
// bf16x3 split precision: acc += Ah*Bh + Al*Bh + Ah*Bl.
// 256 blocks x 512 threads; 64x64 tile/block; 8 waves 4x2, wave = 16x32.
// Double-buffered LDS staging with fine-grained vmcnt + raw s_barrier
// (no compiler vmcnt(0) drain) so chunk c+1's global_load_lds stays in
// flight while chunk c computes.
__global__ void __launch_bounds__(512) step_kernel(
    const unsigned short* __restrict__ Ah, const unsigned short* __restrict__ Al,
    const unsigned short* __restrict__ Bh, const unsigned short* __restrict__ Bl,
    const float* __restrict__ bias,
    const float* __restrict__ hprev, float* __restrict__ hnext,
    unsigned short* __restrict__ Nh, unsigned short* __restrict__ Nl,
    float* __restrict__ feat) {
  __shared__ unsigned short lds[2 * 4 * 64 * 64];   // 64 KiB: 2 bufs of sAh|sAl|sBh|sBl
  char* ldsb = (char*)lds;

  const int tid  = threadIdx.x;
  const int lane = tid & 63;
  const int wave = tid >> 6;       // 0..7
  const int wr   = wave >> 1;      // 0..3
  const int wc   = wave & 1;       // 0..1
  const int row0 = (blockIdx.x >> 4) << 6;
  const int col0 = (blockIdx.x & 15) << 6;
  const int quad = lane >> 4;
  const int l15  = lane & 15;

  // ---- staging addressing: wave stages rows [8*wave, 8*wave+8) of each 64x64 tile
  // LDS row = 128 B = 8 groups of 16 B; storage group g holds source group g^(row&7)
  const int srow = lane >> 3;
  const int sgrp = (lane & 7) ^ srow;
  const long aoff = (long)(row0 + wave * 8 + srow) * D + sgrp * 8;
  const long boff = (long)(col0 + wave * 8 + srow) * D + sgrp * 8;
  const unsigned short* gAh = Ah + aoff;
  const unsigned short* gAl = Al + aoff;
  const unsigned short* gBh = Bh + boff;
  const unsigned short* gBl = Bl + boff;
  const int sw = wave * 1024;      // wave-uniform LDS dest base offset

  // ---- epilogue prefetch: hprev + bias into registers before the K-loop ----
  const int ecol = col0 + (wc << 5) + l15;
  const int erow = row0 + (wr << 4) + (quad << 2);
  float hp0[4], hp1[4];
#pragma unroll
  for (int r = 0; r < 4; ++r) {
    const long i0 = (long)(erow + r) * D + ecol;
    hp0[r] = hprev[i0];
    hp1[r] = hprev[i0 + 16];
  }
  const float b0 = bias[ecol];
  const float b1 = bias[ecol + 16];

  // ---- fragment addressing ----
  const int Ra  = (wr << 4) | l15;
  const int Rb0 = (wc << 5) | l15;
  const int Rb1 = Rb0 + 16;
  const int x7  = lane & 7;

  floatx4 acc0 = {0.f, 0.f, 0.f, 0.f};
  floatx4 acc1 = {0.f, 0.f, 0.f, 0.f};

  // preload chunk 0 -> buffer 0
  gload_lds16(gAh, ldsb + 0     + sw);
  gload_lds16(gAl, ldsb + 8192  + sw);
  gload_lds16(gBh, ldsb + 16384 + sw);
  gload_lds16(gBl, ldsb + 24576 + sw);

  for (int c = 0; c < 16; ++c) {
    const int cur = (c & 1) << 15;               // 0 or 32768
    if (c < 15) {
      const int nxt = ((c + 1) & 1) << 15;
      const int kk = (c + 1) << 6;
      gload_lds16(gAh + kk, ldsb + nxt + 0     + sw);
      gload_lds16(gAl + kk, ldsb + nxt + 8192  + sw);
      gload_lds16(gBh + kk, ldsb + nxt + 16384 + sw);
      gload_lds16(gBl + kk, ldsb + nxt + 24576 + sw);
      // wait only for chunk c's 4 loads; keep the 4 prefetches in flight
      asm volatile("s_waitcnt vmcnt(4)" ::: "memory");
    } else {
      asm volatile("s_waitcnt vmcnt(0)" ::: "memory");
    }
    asm volatile("s_barrier" ::: "memory");       // data-arrival barrier
#pragma unroll
    for (int kc = 0; kc < 2; ++kc) {
      const int gs = (((kc << 2) | quad) ^ x7) << 4;
      const char* base = ldsb + cur;
      bf16x8 ah  = *(const bf16x8*)(base + 0     + Ra  * 128 + gs);
      bf16x8 al  = *(const bf16x8*)(base + 8192  + Ra  * 128 + gs);
      bf16x8 bh0 = *(const bf16x8*)(base + 16384 + Rb0 * 128 + gs);
      bf16x8 bl0 = *(const bf16x8*)(base + 24576 + Rb0 * 128 + gs);
      bf16x8 bh1 = *(const bf16x8*)(base + 16384 + Rb1 * 128 + gs);
      bf16x8 bl1 = *(const bf16x8*)(base + 24576 + Rb1 * 128 + gs);
      acc0 = __builtin_amdgcn_mfma_f32_16x16x32_bf16(ah, bh0, acc0, 0, 0, 0);
      acc1 = __builtin_amdgcn_mfma_f32_16x16x32_bf16(ah, bh1, acc1, 0, 0, 0);
      acc0 = __builtin_amdgcn_mfma_f32_16x16x32_bf16(al, bh0, acc0, 0, 0, 0);
      acc1 = __builtin_amdgcn_mfma_f32_16x16x32_bf16(al, bh1, acc1, 0, 0, 0);
      acc0 = __builtin_amdgcn_mfma_f32_16x16x32_bf16(ah, bl0, acc0, 0, 0, 0);
      acc1 = __builtin_amdgcn_mfma_f32_16x16x32_bf16(ah, bl1, acc1, 0, 0, 0);
    }
    asm volatile("s_barrier" ::: "memory");       // reads done before next overwrite
  }

  // ---- epilogue: bias + tanh + Euler update; fp32 traj + bf16 hi/lo state ----
  const bool wf = (feat != nullptr);
#pragma unroll
  for (int r = 0; r < 4; ++r) {
    const long i0 = (long)(erow + r) * D + ecol;
    {
      float f  = fast_tanh(acc0[r] + b0);
      float hn = hp0[r] + DT * f;
      hnext[i0] = hn;
      unsigned short hb = f2bf(hn);
      Nh[i0] = hb;
      Nl[i0] = f2bf(hn - bf2f(hb));
      if (wf) feat[i0] = hn;
    }
    {
      const long i1 = i0 + 16;
      float f  = fast_tanh(acc1[r] + b1);
      float hn = hp1[r] + DT * f;
      hnext[i1] = hn;
      unsigned short hb = f2bf(hn);
      Nh[i1] = hb;
      Nl[i1] = f2bf(hn - bf2f(hb));
      if (wf) feat[i1] = hn;
    }
  }
}

extern "C" void kernel_launch(void* const* d_in, const int* in_sizes, int n_in,
                              void* d_out, int out_size, void* d_ws, size_t ws_size,
                              hipStream_t stream) {
  const float* x = (const float*)d_in[0];
  const float* W = (const float*)d_in[1];
  const float* b = (const float*)d_in[2];
  float* out  = (float*)d_out;
  float* feat = out;                       // [1024,1024] final features
  float* traj = out + (size_t)D * D;       // [101,1024,1024]

  const size_t M = (size_t)D * D;          // 1M elements
  unsigned short* ws = (unsigned short*)d_ws;
  const int splitBlocks = (int)(M / 4 / 256);   // 1024

  const bool big = ws_size >= (size_t)48 * 1024 * 1024;

  if (big) {
    // layout: Whi[10*M] | Wlo[10*M] | h hi/lo double buffers [4*M]  = 48 MB
    unsigned short* wh_all = ws;
    unsigned short* wl_all = wh_all + 10 * M;
    unsigned short* hbuf   = wl_all + 10 * M;
    unsigned short* hh[2] = {hbuf, hbuf + 2 * M};
    unsigned short* hl[2] = {hbuf + M, hbuf + 3 * M};

    // convert all 10 W slabs up-front (one launch), and seed h state + traj[0]
    split_kernel<<<splitBlocks * 10, 256, 0, stream>>>(W, (float*)nullptr, wh_all, wl_all);
    split_kernel<<<splitBlocks, 256, 0, stream>>>(x, traj, hh[0], hl[0]);

    for (int n = 0; n < 100; ++n) {
      const int k = n / 10;
      step_kernel<<<256, 512, 0, stream>>>(
          hh[n & 1], hl[n & 1], wh_all + (size_t)k * M, wl_all + (size_t)k * M,
          b + (size_t)k * D,
          traj + (size_t)n * M, traj + (size_t)(n + 1) * M,
          hh[(n + 1) & 1], hl[(n + 1) & 1],
          (n == 99) ? feat : nullptr);
    }
  } else {
    // fallback: per-slab W conversion (12 MB ws)
    unsigned short* wh    = ws;
    unsigned short* wl    = wh + M;
    unsigned short* hbuf  = wl + M;
    unsigned short* hh[2] = {hbuf, hbuf + 2 * M};
    unsigned short* hl[2] = {hbuf + M, hbuf + 3 * M};

    split_kernel<<<splitBlocks, 256, 0, stream>>>(x, traj, hh[0], hl[0]);
    for (int k = 0; k < 10; ++k) {
      split_kernel<<<splitBlocks, 256, 0, stream>>>(W + k * M, (float*)nullptr, wh, wl);
      for (int s = 0; s < 10; ++s) {
        const int n = k * 10 + s;
        step_kernel<<<256, 512, 0, stream>>>(
            hh[n & 1], hl[n & 1], wh, wl, b + (size_t)k * D,
            traj + (size_t)n * M, traj + (size_t)(n + 1) * M,
            hh[(n + 1) & 1], hl[(n + 1) & 1],
            (n == 99) ? feat : nullptr);
      }
    }
  }
}